// Round 10
// baseline (834.269 us; speedup 1.0000x reference)
//
#include <hip/hip_runtime.h>
#include <hip/hip_bf16.h>
#include <math.h>

typedef __bf16 bf16_t;
typedef bf16_t bf16x8 __attribute__((ext_vector_type(8)));
typedef bf16_t bf16x4 __attribute__((ext_vector_type(4)));
typedef float f32x4 __attribute__((ext_vector_type(4)));

#define DEVINL __device__ __forceinline__

DEVINL float wave_reduce_sum(float v) {
#pragma unroll
  for (int o = 32; o > 0; o >>= 1) v += __shfl_down(v, o);
  return v;
}
// 256-thread block reduction; red[] >= 4 floats. Leading sync protects reuse.
DEVINL float block_reduce_sum256(float v, float* red) {
  int tid = threadIdx.x;
  __syncthreads();
  v = wave_reduce_sum(v);
  if ((tid & 63) == 0) red[tid >> 6] = v;
  __syncthreads();
  return red[0] + red[1] + red[2] + red[3];
}

// -------- LayerNorm fine: one WAVE per row (no barriers), 4 rows/block ------
__global__ __launch_bounds__(256) void k_ln_fine(const float* __restrict__ x,
                                                 const float* __restrict__ g,
                                                 const float* __restrict__ b,
                                                 bf16_t* __restrict__ out) {
  constexpr int COLS = 1024;
  const int w = threadIdx.x >> 6, l = threadIdx.x & 63;
  const size_t row = (size_t)blockIdx.x * 4 + w;
  const float* xr = x + row * COLS + l * 16;
  float4 v[4];
#pragma unroll
  for (int k = 0; k < 4; k++) v[k] = *(const float4*)(xr + k * 4);
  float s = 0;
#pragma unroll
  for (int k = 0; k < 4; k++) s += v[k].x + v[k].y + v[k].z + v[k].w;
#pragma unroll
  for (int o = 32; o > 0; o >>= 1) s += __shfl_xor(s, o);
  const float mu = s * (1.0f / COLS);
  float q = 0;
#pragma unroll
  for (int k = 0; k < 4; k++) {
    const float d0 = v[k].x - mu, d1 = v[k].y - mu, d2 = v[k].z - mu, d3 = v[k].w - mu;
    q += d0 * d0 + d1 * d1 + d2 * d2 + d3 * d3;
  }
#pragma unroll
  for (int o = 32; o > 0; o >>= 1) q += __shfl_xor(q, o);
  const float rs = rsqrtf(q * (1.0f / COLS) + 1e-5f);
  const int c0 = l * 16;
  bf16x8 o0, o1;
#pragma unroll
  for (int k = 0; k < 4; k++) {
    const float4 gg = *(const float4*)(g + c0 + k * 4);
    const float4 bb = *(const float4*)(b + c0 + k * 4);
    const float r0 = (v[k].x - mu) * rs * gg.x + bb.x;
    const float r1 = (v[k].y - mu) * rs * gg.y + bb.y;
    const float r2 = (v[k].z - mu) * rs * gg.z + bb.z;
    const float r3 = (v[k].w - mu) * rs * gg.w + bb.w;
    if (k < 2) {
      o0[k * 4 + 0] = (bf16_t)r0; o0[k * 4 + 1] = (bf16_t)r1;
      o0[k * 4 + 2] = (bf16_t)r2; o0[k * 4 + 3] = (bf16_t)r3;
    } else {
      o1[(k - 2) * 4 + 0] = (bf16_t)r0; o1[(k - 2) * 4 + 1] = (bf16_t)r1;
      o1[(k - 2) * 4 + 2] = (bf16_t)r2; o1[(k - 2) * 4 + 3] = (bf16_t)r3;
    }
  }
  bf16_t* op = out + row * COLS + c0;
  *(bf16x8*)op = o0;
  *(bf16x8*)(op + 8) = o1;
}

// -------- merged prep: 3 transposes + 2 folds + global LN in one launch ----
// blocks [0,1024) w1t | [1024,1536) w2t | [1536,2560) fpt | [2560,2564) folds
// | [2564,2628) LN(x_global)
__global__ __launch_bounds__(256) void k_prep(
    const float* __restrict__ ip_w1, const float* __restrict__ ip_w2,
    const float* __restrict__ fp_w, const float* __restrict__ gat_wd,
    const float* __restrict__ att_d, const float* __restrict__ gat_ws,
    const float* __restrict__ att_s, const float* __restrict__ x_global,
    const float* __restrict__ ng_g, const float* __restrict__ ng_b,
    bf16_t* __restrict__ w1t, bf16_t* __restrict__ w2t, bf16_t* __restrict__ fpt,
    float* __restrict__ wd_att, float* __restrict__ wsatt, float* __restrict__ xg) {
  __shared__ float t[32][33];
  __shared__ float red[8];
  const int bid = blockIdx.x, tid = threadIdx.x;
  if (bid < 2560) {  // transpose+cast fp32[K][N] -> bf16[N][K]
    const float* src;
    bf16_t* dst;
    int N, n0, k0;
    if (bid < 1024) {
      src = ip_w1; dst = w1t; N = 1024;
      n0 = (bid & 31) * 32; k0 = (bid >> 5) * 32;
    } else if (bid < 1536) {
      const int rel = bid - 1024;
      src = ip_w2; dst = w2t; N = 512;
      n0 = (rel & 15) * 32; k0 = (rel >> 4) * 32;
    } else {
      const int rel = bid - 1536;
      src = fp_w; dst = fpt; N = 2048;
      n0 = (rel & 63) * 32; k0 = (rel >> 6) * 32;
    }
    const int K = (bid < 1536) ? 1024 : 512;
    const int tx = tid & 31, ty = tid >> 5;
#pragma unroll
    for (int i = 0; i < 32; i += 8)
      t[ty + i][tx] = src[(size_t)(k0 + ty + i) * N + n0 + tx];
    __syncthreads();
#pragma unroll
    for (int i = 0; i < 32; i += 8)
      dst[(size_t)(n0 + ty + i) * K + k0 + tx] = (bf16_t)t[tx][ty + i];
  } else if (bid < 2564) {  // folds: out[k*8+h] = sum_c W[k,h*64+c]*att[h*64+c]
    const int rel = bid - 2560;
    const float* W = (rel < 2) ? gat_wd : gat_ws;
    const float* att = (rel < 2) ? att_d : att_s;
    float* outp = (rel < 2) ? wd_att : wsatt;
    const int k = (rel & 1) * 256 + tid;
#pragma unroll
    for (int h = 0; h < 8; h++) {
      float s = 0;
      for (int c = 0; c < 64; c++)
        s += W[(size_t)k * 512 + h * 64 + c] * att[h * 64 + c];
      outp[k * 8 + h] = s;
    }
  } else {  // LN of x_global row (CPT=2, 512 cols) -> fp32 xg
    const int row = bid - 2564;
    const float* xr = x_global + (size_t)row * 512;
    const int c0 = tid * 2;
    float v0 = xr[c0], v1 = xr[c0 + 1];
    const float mu = block_reduce_sum256(v0 + v1, red) * (1.0f / 512);
    const float d0 = v0 - mu, d1 = v1 - mu;
    const float var = block_reduce_sum256(d0 * d0 + d1 * d1, red) * (1.0f / 512);
    const float rs = rsqrtf(var + 1e-5f);
    xg[(size_t)row * 512 + c0] = d0 * rs * ng_g[c0] + ng_b[c0];
    xg[(size_t)row * 512 + c0 + 1] = d1 * rs * ng_g[c0 + 1] + ng_b[c0 + 1];
  }
}

// ---------------- MFMA bf16 GEMM, C = A[M,K] * Bt[N,K]^T (R9 winner) --------
// 128x128 tile, BK=64, 4 waves (2x2), global_load_lds staging (m97 structure).
// XCD-AFFINE 1-D grid remap: all NBY blocks sharing an A-panel (same bx) are
// congruent mod 8 (same XCD, ~8 dispatches apart) -> A-panel staged from
// HBM/L3 once, re-read NBY-1 times from that XCD's L2.
// d = (bx&7) + 8*by + 8*NBY*(bx>>3)  [bijective; M/128=512 divisible by 8]
// EPI: 0 = bias+relu -> bf16 ; 1 = bias -> bf16 ;
//      3 = bias -> fp32, strided output row r -> r + (r>>10) + 1 (of-layout)
template <int N, int K, int EPI>
__global__ __launch_bounds__(256, 2) void gemm_bt(const bf16_t* __restrict__ A,
                                                  const bf16_t* __restrict__ Bt,
                                                  const float* __restrict__ bias,
                                                  void* __restrict__ Cout) {
  __shared__ bf16_t As[128 * 64];
  __shared__ bf16_t Bs[128 * 64];
  constexpr int NBY = N / 128;
  const int d = blockIdx.x;
  const int bx = (d & 7) + 8 * (d / (8 * NBY));
  const int by = (d >> 3) % NBY;
  const int tid = threadIdx.x;
  const int lane = tid & 63;
  const int wid = tid >> 6;
  const int wm = wid >> 1, wn = wid & 1;
  const size_t arow0 = (size_t)bx * 128;
  const int bcol0 = by * 128;

  f32x4 acc[4][4] = {};
  const int kTiles = K / 64;
  for (int kt = 0; kt < kTiles; ++kt) {
    const int k0 = kt * 64;
#pragma unroll
    for (int i = 0; i < 4; ++i) {
      const int c = i * 256 + tid;
      const int r = c >> 3, kc = (c & 7) * 8;
      const bf16_t* ga = A + (arow0 + r) * K + k0 + kc;
      __builtin_amdgcn_global_load_lds(
          (const __attribute__((address_space(1))) void*)ga,
          (__attribute__((address_space(3))) void*)(As + c * 8), 16, 0, 0);
      const bf16_t* gb = Bt + ((size_t)bcol0 + r) * K + k0 + kc;
      __builtin_amdgcn_global_load_lds(
          (const __attribute__((address_space(1))) void*)gb,
          (__attribute__((address_space(3))) void*)(Bs + c * 8), 16, 0, 0);
    }
    __syncthreads();
#pragma unroll
    for (int kk = 0; kk < 2; ++kk) {
      bf16x8 af[4], bfr[4];
      const int kofs = kk * 32 + (lane >> 4) * 8;
#pragma unroll
      for (int m = 0; m < 4; ++m)
        af[m] = *(const bf16x8*)(As + (wm * 64 + m * 16 + (lane & 15)) * 64 + kofs);
#pragma unroll
      for (int n = 0; n < 4; ++n)
        bfr[n] = *(const bf16x8*)(Bs + (wn * 64 + n * 16 + (lane & 15)) * 64 + kofs);
#pragma unroll
      for (int m = 0; m < 4; ++m)
#pragma unroll
        for (int n = 0; n < 4; ++n)
          acc[m][n] = __builtin_amdgcn_mfma_f32_16x16x32_bf16(af[m], bfr[n], acc[m][n], 0, 0, 0);
    }
    __syncthreads();
  }
  // epilogue: D lane mapping col = lane&15, row = (lane>>4)*4 + j
  const int lr = (lane >> 4) * 4;
  const int lc = lane & 15;
#pragma unroll
  for (int n = 0; n < 4; ++n) {
    const int col = bcol0 + wn * 64 + n * 16 + lc;
    const float bv = bias[col];
#pragma unroll
    for (int m = 0; m < 4; ++m) {
#pragma unroll
      for (int j = 0; j < 4; ++j) {
        const size_t row = arow0 + wm * 64 + m * 16 + lr + j;
        float v = acc[m][n][j] + bv;
        if constexpr (EPI == 0) v = v > 0.0f ? v : 0.0f;
        if constexpr (EPI == 3) {
          const size_t orow = row + (row >> 10) + 1;
          ((float*)Cout)[orow * (size_t)N + col] = v;
        } else {
          ((bf16_t*)Cout)[row * (size_t)N + col] = (bf16_t)v;
        }
      }
    }
  }
}

// ---- a_s[i,h] = xf[i,:] . wsatt[:,h]  (wsatt [512][8] contiguous) ----
__global__ __launch_bounds__(256) void k_as(const bf16_t* __restrict__ xf,
                                            const float* __restrict__ wsatt,
                                            float* __restrict__ a_s) {
  const int tid = threadIdx.x, l = tid & 63, wid = tid >> 6;
  float wreg[64];
#pragma unroll
  for (int q = 0; q < 16; q++) {
    const float4 v = *(const float4*)(wsatt + l * 64 + q * 4);
    wreg[q * 4 + 0] = v.x; wreg[q * 4 + 1] = v.y;
    wreg[q * 4 + 2] = v.z; wreg[q * 4 + 3] = v.w;
  }
  const size_t base = (size_t)blockIdx.x * 128 + wid * 32;
  for (int rr = 0; rr < 32; rr++) {
    const size_t i = base + rr;
    const bf16x8 v = *(const bf16x8*)(xf + i * 512 + l * 8);
    float p[8] = {};
#pragma unroll
    for (int u = 0; u < 8; u++) {
      const float xv = (float)v[u];
#pragma unroll
      for (int h = 0; h < 8; h++) p[h] += xv * wreg[u * 8 + h];
    }
#pragma unroll
    for (int h = 0; h < 8; h++)
#pragma unroll
      for (int mk = 1; mk < 64; mk <<= 1) p[h] += __shfl_xor(p[h], mk);
    float outv = 0.0f;
#pragma unroll
    for (int h = 0; h < 8; h++) outv = (l == h) ? p[h] : outv;
    if (l < 8) a_s[i * 8 + l] = outv;
  }
}

// ---- per-graph softmax + quarter-z accumulation: block = (b, quarter q) ----
// zq[b,q,h,:] = sum_{i in quarter} alpha[i,h]*xf[b*1024+i,:] (+ self in q==0)
__global__ __launch_bounds__(512) void k_alpha_z(const float* __restrict__ a_s,
                                                 const bf16_t* __restrict__ xf,
                                                 const float* __restrict__ xg,
                                                 const float* __restrict__ wd_att,
                                                 float* __restrict__ zq) {
  __shared__ float sal[8][260];
  const int b = blockIdx.x >> 2, qq = blockIdx.x & 3;
  const int tid = threadIdx.x, l = tid & 63, h = tid >> 6;
  // a_d for head h (all lanes end with total)
  float pa = 0;
#pragma unroll
  for (int u = 0; u < 8; u++)
    pa += xg[b * 512 + l * 8 + u] * wd_att[(l * 8 + u) * 8 + h];
#pragma unroll
  for (int mk = 1; mk < 64; mk <<= 1) pa += __shfl_xor(pa, mk);
  const float ad = pa;
  // full softmax over all 1024 entries (+self); keep own quarter's alphas
  const float* asb = a_s + (size_t)b * 1024 * 8;
  float lg[16];
  float lmax = -1e30f;
#pragma unroll
  for (int j = 0; j < 16; j++) {
    const float a = asb[(l + j * 64) * 8 + h] + ad;
    lg[j] = a > 0.0f ? a : 0.2f * a;
    lmax = fmaxf(lmax, lg[j]);
  }
  float lself = -INFINITY;  // b==0: masked edge cancels the self-loop
  if (l == 0 && b != 0) {
    const float a = a_s[b * 8 + h] + ad;  // self uses FINE node b (ref quirk)
    lself = a > 0.0f ? a : 0.2f * a;
  }
  lmax = fmaxf(lmax, lself);
#pragma unroll
  for (int mk = 1; mk < 64; mk <<= 1) lmax = fmaxf(lmax, __shfl_xor(lmax, mk));
  float ps = 0;
#pragma unroll
  for (int j = 0; j < 16; j++) { lg[j] = __expf(lg[j] - lmax); ps += lg[j]; }
  const float eself = (l == 0 && lself != -INFINITY) ? __expf(lself - lmax) : 0.0f;
  ps += eself;
#pragma unroll
  for (int mk = 1; mk < 64; mk <<= 1) ps += __shfl_xor(ps, mk);
  const float inv = 1.0f / ps;
#pragma unroll
  for (int j = 0; j < 4; j++) sal[h][l + j * 64] = lg[qq * 4 + j] * inv;
  if (l == 0) sal[h][256] = (qq == 0) ? eself * inv : 0.0f;
  __syncthreads();
  // weighted accumulation over this quarter's 256 rows; lane owns 8 cols
  float zp[8] = {};
  const bf16_t* xb = xf + ((size_t)b * 1024 + qq * 256) * 512 + l * 8;
  for (int i = 0; i < 256; i += 2) {
    const float a0 = sal[h][i], a1 = sal[h][i + 1];
    const bf16x8 v0 = *(const bf16x8*)(xb + (size_t)i * 512);
    const bf16x8 v1 = *(const bf16x8*)(xb + (size_t)(i + 1) * 512);
#pragma unroll
    for (int u = 0; u < 8; u++) zp[u] += a0 * (float)v0[u] + a1 * (float)v1[u];
  }
  if (qq == 0) {
    const float a = sal[h][256];
    const bf16x8 v = *(const bf16x8*)(xf + (size_t)b * 512 + l * 8);
#pragma unroll
    for (int u = 0; u < 8; u++) zp[u] += a * (float)v[u];
  }
  float4 o0 = {zp[0], zp[1], zp[2], zp[3]};
  float4 o1 = {zp[4], zp[5], zp[6], zp[7]};
  float* zo = zq + (((size_t)b * 4 + qq) * 8 + h) * 512 + l * 8;
  *(float4*)zo = o0;
  *(float4*)(zo + 4) = o1;
}

// ---- fused fin+og: aggx = (sum_q zq)@ws + bias + xg ; out[b,0,:] = aggx@gp_w
__global__ __launch_bounds__(512) void k_finog(const float* __restrict__ zq,
                                               const float* __restrict__ ws,
                                               const float* __restrict__ gat_bias,
                                               const float* __restrict__ xg,
                                               const float* __restrict__ gp_w,
                                               const float* __restrict__ gp_b,
                                               float* __restrict__ out) {
  __shared__ float zsum[4096];
  __shared__ float aggx[512];
  const int b = blockIdx.x, c = threadIdx.x, h = c >> 6;
  const float* zb = zq + (size_t)b * 4 * 4096;
  for (int idx = c; idx < 4096; idx += 512)
    zsum[idx] = zb[idx] + zb[4096 + idx] + zb[8192 + idx] + zb[12288 + idx];
  __syncthreads();
  const float* zr = zsum + h * 512;
  float acc = 0;
#pragma unroll 8
  for (int k = 0; k < 512; k++) acc += zr[k] * ws[(size_t)k * 512 + c];
  aggx[c] = acc + gat_bias[c] + xg[b * 512 + c];
  __syncthreads();
#pragma unroll
  for (int j = 0; j < 4; j++) {
    const int cc = c + j * 512;
    float o = gp_b[cc];
#pragma unroll 8
    for (int k = 0; k < 512; k++) o += aggx[k] * gp_w[(size_t)k * 2048 + cc];
    out[(size_t)b * 1025 * 2048 + cc] = o;
  }
}

extern "C" void kernel_launch(void* const* d_in, const int* in_sizes, int n_in,
                              void* d_out, int out_size, void* d_ws, size_t ws_size,
                              hipStream_t stream) {
  const float* x_fine   = (const float*)d_in[0];
  const float* x_global = (const float*)d_in[1];
  // d_in[2]: edge_index — structure is static (i -> i/1024), not needed
  const float* nf_g  = (const float*)d_in[3];
  const float* nf_b  = (const float*)d_in[4];
  const float* ip_w1 = (const float*)d_in[5];
  const float* ip_b1 = (const float*)d_in[6];
  const float* ip_w2 = (const float*)d_in[7];
  const float* ip_b2 = (const float*)d_in[8];
  const float* ng_g  = (const float*)d_in[9];
  const float* ng_b  = (const float*)d_in[10];
  const float* gat_ws   = (const float*)d_in[11];
  const float* gat_wd   = (const float*)d_in[12];
  const float* att_s    = (const float*)d_in[13];
  const float* att_d    = (const float*)d_in[14];
  const float* gat_bias = (const float*)d_in[15];
  const float* gp_w = (const float*)d_in[16];
  const float* gp_b = (const float*)d_in[17];
  const float* fp_w = (const float*)d_in[18];
  const float* fp_b = (const float*)d_in[19];
  float* out = (float*)d_out;

  char* ws = (char*)d_ws;
  bf16_t* xf_ln = (bf16_t*)ws;                   // [65536,1024] bf16; later xf [65536,512]
  bf16_t* hbuf  = (bf16_t*)(ws + 134217728ULL);  // [65536,1024] bf16
  char* sm = ws + 268435456ULL;
  bf16_t* w1t  = (bf16_t*)sm;                    // [1024,1024] 2 MiB
  bf16_t* w2t  = (bf16_t*)(sm + 2097152ULL);     // [512,1024] 1 MiB
  bf16_t* fpt  = (bf16_t*)(sm + 3145728ULL);     // [2048,512] 2 MiB
  float*  a_s  = (float*)(sm + 5242880ULL);      // [65536,8] 2 MiB
  float*  xg   = (float*)(sm + 7340032ULL);      // [64,512] 128 KiB
  float*  wd_att = (float*)(sm + 7471104ULL);    // [512,8] 16 KiB
  float*  wsatt  = (float*)(sm + 7487488ULL);    // [512,8] 16 KiB
  float*  zbuf4  = (float*)(sm + 7503872ULL);    // [64,4,8,512] 4 MiB
  bf16_t* xf = xf_ln;  // [65536,512] after G2 (xf_ln dead)

  // merged weight prep + global LN
  k_prep<<<2628, 256, 0, stream>>>(ip_w1, ip_w2, fp_w, gat_wd, att_d, gat_ws,
                                   att_s, x_global, ng_g, ng_b, w1t, w2t, fpt,
                                   wd_att, wsatt, xg);

  // fine LN (wave-per-row, barrier-free)
  k_ln_fine<<<16384, 256, 0, stream>>>(x_fine, nf_g, nf_b, xf_ln);

  // MLP (m97-structure MFMA GEMMs, XCD-affine A-panel grouping)
  gemm_bt<1024, 1024, 0><<<4096, 256, 0, stream>>>(xf_ln, w1t, ip_b1, hbuf);
  gemm_bt<512, 1024, 1><<<2048, 256, 0, stream>>>(hbuf, w2t, ip_b2, xf);

  // attention chain (GEMM3 eliminated by linearity of gat_ws)
  k_as<<<512, 256, 0, stream>>>(xf, wsatt, a_s);
  k_alpha_z<<<256, 512, 0, stream>>>(a_s, xf, xg, wd_att, zbuf4);
  k_finog<<<64, 512, 0, stream>>>(zbuf4, gat_ws, gat_bias, xg, gp_w, gp_b, out);

  // fine projection straight into strided output rows
  gemm_bt<2048, 512, 3><<<8192, 256, 0, stream>>>(xf, fpt, fp_b, out);
}

// Round 11
// 724.615 us; speedup vs baseline: 1.1513x; 1.1513x over previous
//
#include <hip/hip_runtime.h>
#include <hip/hip_bf16.h>
#include <math.h>

typedef __bf16 bf16_t;
typedef bf16_t bf16x8 __attribute__((ext_vector_type(8)));
typedef bf16_t bf16x4 __attribute__((ext_vector_type(4)));
typedef float f32x4 __attribute__((ext_vector_type(4)));

#define DEVINL __device__ __forceinline__

DEVINL float wave_reduce_sum(float v) {
#pragma unroll
  for (int o = 32; o > 0; o >>= 1) v += __shfl_down(v, o);
  return v;
}
// 256-thread block reduction; red[] >= 4 floats. Leading sync protects reuse.
DEVINL float block_reduce_sum256(float v, float* red) {
  int tid = threadIdx.x;
  __syncthreads();
  v = wave_reduce_sum(v);
  if ((tid & 63) == 0) red[tid >> 6] = v;
  __syncthreads();
  return red[0] + red[1] + red[2] + red[3];
}

// ---------------- LayerNorm fine (one block per row, 256 threads) -----------
// coalesced: thread tid owns 4 consecutive cols (float4); consecutive threads
// -> consecutive 16B (R10's wave-per-row variant broke this: 64B-stride/lane).
__global__ __launch_bounds__(256) void k_ln_fine(const float* __restrict__ x,
                                                 const float* __restrict__ g,
                                                 const float* __restrict__ b,
                                                 bf16_t* __restrict__ out) {
  constexpr int COLS = 1024;
  __shared__ float red[8];
  const size_t row = blockIdx.x;
  const float* xr = x + row * COLS;
  const int c0 = threadIdx.x * 4;
  const float4 vv = *(const float4*)(xr + c0);
  const float4 gg = *(const float4*)(g + c0);
  const float4 bb = *(const float4*)(b + c0);
  float v[4] = {vv.x, vv.y, vv.z, vv.w};
  float s = v[0] + v[1] + v[2] + v[3];
  const float mu = block_reduce_sum256(s, red) * (1.0f / COLS);
  float q = 0;
#pragma unroll
  for (int j = 0; j < 4; j++) { float d = v[j] - mu; q += d * d; }
  const float var = block_reduce_sum256(q, red) * (1.0f / COLS);
  const float rs = rsqrtf(var + 1e-5f);
  const float gv[4] = {gg.x, gg.y, gg.z, gg.w};
  const float bv[4] = {bb.x, bb.y, bb.z, bb.w};
  bf16x4 o;
#pragma unroll
  for (int j = 0; j < 4; j++)
    o[j] = (bf16_t)((v[j] - mu) * rs * gv[j] + bv[j]);
  *(bf16x4*)(out + row * COLS + c0) = o;
}

// -------- merged prep: 3 transposes + 2 folds + global LN in one launch ----
// blocks [0,1024) w1t | [1024,1536) w2t | [1536,2560) fpt | [2560,2564) folds
// | [2564,2628) LN(x_global)
__global__ __launch_bounds__(256) void k_prep(
    const float* __restrict__ ip_w1, const float* __restrict__ ip_w2,
    const float* __restrict__ fp_w, const float* __restrict__ gat_wd,
    const float* __restrict__ att_d, const float* __restrict__ gat_ws,
    const float* __restrict__ att_s, const float* __restrict__ x_global,
    const float* __restrict__ ng_g, const float* __restrict__ ng_b,
    bf16_t* __restrict__ w1t, bf16_t* __restrict__ w2t, bf16_t* __restrict__ fpt,
    float* __restrict__ wd_att, float* __restrict__ wsatt, float* __restrict__ xg) {
  __shared__ float t[32][33];
  __shared__ float red[8];
  const int bid = blockIdx.x, tid = threadIdx.x;
  if (bid < 2560) {  // transpose+cast fp32[K][N] -> bf16[N][K]
    const float* src;
    bf16_t* dst;
    int N, n0, k0;
    if (bid < 1024) {
      src = ip_w1; dst = w1t; N = 1024;
      n0 = (bid & 31) * 32; k0 = (bid >> 5) * 32;
    } else if (bid < 1536) {
      const int rel = bid - 1024;
      src = ip_w2; dst = w2t; N = 512;
      n0 = (rel & 15) * 32; k0 = (rel >> 4) * 32;
    } else {
      const int rel = bid - 1536;
      src = fp_w; dst = fpt; N = 2048;
      n0 = (rel & 63) * 32; k0 = (rel >> 6) * 32;
    }
    const int K = (bid < 1536) ? 1024 : 512;
    const int tx = tid & 31, ty = tid >> 5;
#pragma unroll
    for (int i = 0; i < 32; i += 8)
      t[ty + i][tx] = src[(size_t)(k0 + ty + i) * N + n0 + tx];
    __syncthreads();
#pragma unroll
    for (int i = 0; i < 32; i += 8)
      dst[(size_t)(n0 + ty + i) * K + k0 + tx] = (bf16_t)t[tx][ty + i];
  } else if (bid < 2564) {  // folds: out[k*8+h] = sum_c W[k,h*64+c]*att[h*64+c]
    const int rel = bid - 2560;
    const float* W = (rel < 2) ? gat_wd : gat_ws;
    const float* att = (rel < 2) ? att_d : att_s;
    float* outp = (rel < 2) ? wd_att : wsatt;
    const int k = (rel & 1) * 256 + tid;
#pragma unroll
    for (int h = 0; h < 8; h++) {
      float s = 0;
      for (int c = 0; c < 64; c++)
        s += W[(size_t)k * 512 + h * 64 + c] * att[h * 64 + c];
      outp[k * 8 + h] = s;
    }
  } else {  // LN of x_global row (CPT=2, 512 cols) -> fp32 xg
    const int row = bid - 2564;
    const float* xr = x_global + (size_t)row * 512;
    const int c0 = tid * 2;
    float v0 = xr[c0], v1 = xr[c0 + 1];
    const float mu = block_reduce_sum256(v0 + v1, red) * (1.0f / 512);
    const float d0 = v0 - mu, d1 = v1 - mu;
    const float var = block_reduce_sum256(d0 * d0 + d1 * d1, red) * (1.0f / 512);
    const float rs = rsqrtf(var + 1e-5f);
    xg[(size_t)row * 512 + c0] = d0 * rs * ng_g[c0] + ng_b[c0];
    xg[(size_t)row * 512 + c0 + 1] = d1 * rs * ng_g[c0 + 1] + ng_b[c0 + 1];
  }
}

// ---------------- MFMA bf16 GEMM, C = A[M,K] * Bt[N,K]^T (R9 winner) --------
// 128x128 tile, BK=64, 4 waves (2x2), global_load_lds staging (m97 structure).
// XCD-AFFINE 1-D grid remap: all NBY blocks sharing an A-panel (same bx) are
// congruent mod 8 (same XCD, ~8 dispatches apart) -> A-panel staged from
// HBM/L3 once, re-read NBY-1 times from that XCD's L2.
// d = (bx&7) + 8*by + 8*NBY*(bx>>3)  [bijective; M/128=512 divisible by 8]
// EPI: 0 = bias+relu -> bf16 ; 1 = bias -> bf16 ;
//      3 = bias -> fp32, strided output row r -> r + (r>>10) + 1 (of-layout)
template <int N, int K, int EPI>
__global__ __launch_bounds__(256, 2) void gemm_bt(const bf16_t* __restrict__ A,
                                                  const bf16_t* __restrict__ Bt,
                                                  const float* __restrict__ bias,
                                                  void* __restrict__ Cout) {
  __shared__ bf16_t As[128 * 64];
  __shared__ bf16_t Bs[128 * 64];
  constexpr int NBY = N / 128;
  const int d = blockIdx.x;
  const int bx = (d & 7) + 8 * (d / (8 * NBY));
  const int by = (d >> 3) % NBY;
  const int tid = threadIdx.x;
  const int lane = tid & 63;
  const int wid = tid >> 6;
  const int wm = wid >> 1, wn = wid & 1;
  const size_t arow0 = (size_t)bx * 128;
  const int bcol0 = by * 128;

  f32x4 acc[4][4] = {};
  const int kTiles = K / 64;
  for (int kt = 0; kt < kTiles; ++kt) {
    const int k0 = kt * 64;
#pragma unroll
    for (int i = 0; i < 4; ++i) {
      const int c = i * 256 + tid;
      const int r = c >> 3, kc = (c & 7) * 8;
      const bf16_t* ga = A + (arow0 + r) * K + k0 + kc;
      __builtin_amdgcn_global_load_lds(
          (const __attribute__((address_space(1))) void*)ga,
          (__attribute__((address_space(3))) void*)(As + c * 8), 16, 0, 0);
      const bf16_t* gb = Bt + ((size_t)bcol0 + r) * K + k0 + kc;
      __builtin_amdgcn_global_load_lds(
          (const __attribute__((address_space(1))) void*)gb,
          (__attribute__((address_space(3))) void*)(Bs + c * 8), 16, 0, 0);
    }
    __syncthreads();
#pragma unroll
    for (int kk = 0; kk < 2; ++kk) {
      bf16x8 af[4], bfr[4];
      const int kofs = kk * 32 + (lane >> 4) * 8;
#pragma unroll
      for (int m = 0; m < 4; ++m)
        af[m] = *(const bf16x8*)(As + (wm * 64 + m * 16 + (lane & 15)) * 64 + kofs);
#pragma unroll
      for (int n = 0; n < 4; ++n)
        bfr[n] = *(const bf16x8*)(Bs + (wn * 64 + n * 16 + (lane & 15)) * 64 + kofs);
#pragma unroll
      for (int m = 0; m < 4; ++m)
#pragma unroll
        for (int n = 0; n < 4; ++n)
          acc[m][n] = __builtin_amdgcn_mfma_f32_16x16x32_bf16(af[m], bfr[n], acc[m][n], 0, 0, 0);
    }
    __syncthreads();
  }
  // epilogue: D lane mapping col = lane&15, row = (lane>>4)*4 + j
  const int lr = (lane >> 4) * 4;
  const int lc = lane & 15;
#pragma unroll
  for (int n = 0; n < 4; ++n) {
    const int col = bcol0 + wn * 64 + n * 16 + lc;
    const float bv = bias[col];
#pragma unroll
    for (int m = 0; m < 4; ++m) {
#pragma unroll
      for (int j = 0; j < 4; ++j) {
        const size_t row = arow0 + wm * 64 + m * 16 + lr + j;
        float v = acc[m][n][j] + bv;
        if constexpr (EPI == 0) v = v > 0.0f ? v : 0.0f;
        if constexpr (EPI == 3) {
          const size_t orow = row + (row >> 10) + 1;
          ((float*)Cout)[orow * (size_t)N + col] = v;
        } else {
          ((bf16_t*)Cout)[row * (size_t)N + col] = (bf16_t)v;
        }
      }
    }
  }
}

// ---- a_s[i,h] = xf[i,:] . wsatt[:,h]  (wsatt [512][8] contiguous) ----
__global__ __launch_bounds__(256) void k_as(const bf16_t* __restrict__ xf,
                                            const float* __restrict__ wsatt,
                                            float* __restrict__ a_s) {
  const int tid = threadIdx.x, l = tid & 63, wid = tid >> 6;
  float wreg[64];
#pragma unroll
  for (int q = 0; q < 16; q++) {
    const float4 v = *(const float4*)(wsatt + l * 64 + q * 4);
    wreg[q * 4 + 0] = v.x; wreg[q * 4 + 1] = v.y;
    wreg[q * 4 + 2] = v.z; wreg[q * 4 + 3] = v.w;
  }
  const size_t base = (size_t)blockIdx.x * 128 + wid * 32;
  for (int rr = 0; rr < 32; rr++) {
    const size_t i = base + rr;
    const bf16x8 v = *(const bf16x8*)(xf + i * 512 + l * 8);
    float p[8] = {};
#pragma unroll
    for (int u = 0; u < 8; u++) {
      const float xv = (float)v[u];
#pragma unroll
      for (int h = 0; h < 8; h++) p[h] += xv * wreg[u * 8 + h];
    }
#pragma unroll
    for (int h = 0; h < 8; h++)
#pragma unroll
      for (int mk = 1; mk < 64; mk <<= 1) p[h] += __shfl_xor(p[h], mk);
    float outv = 0.0f;
#pragma unroll
    for (int h = 0; h < 8; h++) outv = (l == h) ? p[h] : outv;
    if (l < 8) a_s[i * 8 + l] = outv;
  }
}

// ---- per-graph softmax + quarter-z accumulation: block = (b, quarter q) ----
// zq[b,q,h,:] = sum_{i in quarter} alpha[i,h]*xf[b*1024+i,:] (+ self in q==0)
__global__ __launch_bounds__(512) void k_alpha_z(const float* __restrict__ a_s,
                                                 const bf16_t* __restrict__ xf,
                                                 const float* __restrict__ xg,
                                                 const float* __restrict__ wd_att,
                                                 float* __restrict__ zq) {
  __shared__ float sal[8][260];
  const int b = blockIdx.x >> 2, qq = blockIdx.x & 3;
  const int tid = threadIdx.x, l = tid & 63, h = tid >> 6;
  // a_d for head h (all lanes end with total)
  float pa = 0;
#pragma unroll
  for (int u = 0; u < 8; u++)
    pa += xg[b * 512 + l * 8 + u] * wd_att[(l * 8 + u) * 8 + h];
#pragma unroll
  for (int mk = 1; mk < 64; mk <<= 1) pa += __shfl_xor(pa, mk);
  const float ad = pa;
  // full softmax over all 1024 entries (+self); keep own quarter's alphas
  const float* asb = a_s + (size_t)b * 1024 * 8;
  float lg[16];
  float lmax = -1e30f;
#pragma unroll
  for (int j = 0; j < 16; j++) {
    const float a = asb[(l + j * 64) * 8 + h] + ad;
    lg[j] = a > 0.0f ? a : 0.2f * a;
    lmax = fmaxf(lmax, lg[j]);
  }
  float lself = -INFINITY;  // b==0: masked edge cancels the self-loop
  if (l == 0 && b != 0) {
    const float a = a_s[b * 8 + h] + ad;  // self uses FINE node b (ref quirk)
    lself = a > 0.0f ? a : 0.2f * a;
  }
  lmax = fmaxf(lmax, lself);
#pragma unroll
  for (int mk = 1; mk < 64; mk <<= 1) lmax = fmaxf(lmax, __shfl_xor(lmax, mk));
  float ps = 0;
#pragma unroll
  for (int j = 0; j < 16; j++) { lg[j] = __expf(lg[j] - lmax); ps += lg[j]; }
  const float eself = (l == 0 && lself != -INFINITY) ? __expf(lself - lmax) : 0.0f;
  ps += eself;
#pragma unroll
  for (int mk = 1; mk < 64; mk <<= 1) ps += __shfl_xor(ps, mk);
  const float inv = 1.0f / ps;
#pragma unroll
  for (int j = 0; j < 4; j++) sal[h][l + j * 64] = lg[qq * 4 + j] * inv;
  if (l == 0) sal[h][256] = (qq == 0) ? eself * inv : 0.0f;
  __syncthreads();
  // weighted accumulation over this quarter's 256 rows; lane owns 8 cols
  float zp[8] = {};
  const bf16_t* xb = xf + ((size_t)b * 1024 + qq * 256) * 512 + l * 8;
  for (int i = 0; i < 256; i += 2) {
    const float a0 = sal[h][i], a1 = sal[h][i + 1];
    const bf16x8 v0 = *(const bf16x8*)(xb + (size_t)i * 512);
    const bf16x8 v1 = *(const bf16x8*)(xb + (size_t)(i + 1) * 512);
#pragma unroll
    for (int u = 0; u < 8; u++) zp[u] += a0 * (float)v0[u] + a1 * (float)v1[u];
  }
  if (qq == 0) {
    const float a = sal[h][256];
    const bf16x8 v = *(const bf16x8*)(xf + (size_t)b * 512 + l * 8);
#pragma unroll
    for (int u = 0; u < 8; u++) zp[u] += a * (float)v[u];
  }
  float4 o0 = {zp[0], zp[1], zp[2], zp[3]};
  float4 o1 = {zp[4], zp[5], zp[6], zp[7]};
  float* zo = zq + (((size_t)b * 4 + qq) * 8 + h) * 512 + l * 8;
  *(float4*)zo = o0;
  *(float4*)(zo + 4) = o1;
}

// ---- aggx[b,c] = (sum_q zq)[b, c>>6, :] . gat_ws[:, c] + gat_bias + xg ----
__global__ __launch_bounds__(512) void k_fin(const float* __restrict__ zq,
                                             const float* __restrict__ ws,
                                             const float* __restrict__ gat_bias,
                                             const float* __restrict__ xg,
                                             float* __restrict__ aggx) {
  __shared__ float zsum[4096];
  const int b = blockIdx.x, c = threadIdx.x, h = c >> 6;
  const float* zb = zq + (size_t)b * 4 * 4096;
  for (int idx = c; idx < 4096; idx += 512)
    zsum[idx] = zb[idx] + zb[4096 + idx] + zb[8192 + idx] + zb[12288 + idx];
  __syncthreads();
  const float* zr = zsum + h * 512;
  float acc = 0;
#pragma unroll 8
  for (int k = 0; k < 512; k++) acc += zr[k] * ws[(size_t)k * 512 + c];
  aggx[b * 512 + c] = acc + gat_bias[c] + xg[b * 512 + c];
}

// -------- og: out[b,0,:] = aggx[b,:] @ gp_w + gp_b --------
__global__ __launch_bounds__(256) void k_og(const float* __restrict__ aggx,
                                            const float* __restrict__ gp_w,
                                            const float* __restrict__ gp_b,
                                            float* __restrict__ out) {
  __shared__ float xv[512];
  const int b = blockIdx.y;
  const int c = blockIdx.x * 256 + threadIdx.x;
  for (int k = threadIdx.x; k < 512; k += 256) xv[k] = aggx[b * 512 + k];
  __syncthreads();
  float acc = gp_b[c];
#pragma unroll 8
  for (int k = 0; k < 512; k++) acc += xv[k] * gp_w[(size_t)k * 2048 + c];
  out[(size_t)b * 1025 * 2048 + c] = acc;
}

extern "C" void kernel_launch(void* const* d_in, const int* in_sizes, int n_in,
                              void* d_out, int out_size, void* d_ws, size_t ws_size,
                              hipStream_t stream) {
  const float* x_fine   = (const float*)d_in[0];
  const float* x_global = (const float*)d_in[1];
  // d_in[2]: edge_index — structure is static (i -> i/1024), not needed
  const float* nf_g  = (const float*)d_in[3];
  const float* nf_b  = (const float*)d_in[4];
  const float* ip_w1 = (const float*)d_in[5];
  const float* ip_b1 = (const float*)d_in[6];
  const float* ip_w2 = (const float*)d_in[7];
  const float* ip_b2 = (const float*)d_in[8];
  const float* ng_g  = (const float*)d_in[9];
  const float* ng_b  = (const float*)d_in[10];
  const float* gat_ws   = (const float*)d_in[11];
  const float* gat_wd   = (const float*)d_in[12];
  const float* att_s    = (const float*)d_in[13];
  const float* att_d    = (const float*)d_in[14];
  const float* gat_bias = (const float*)d_in[15];
  const float* gp_w = (const float*)d_in[16];
  const float* gp_b = (const float*)d_in[17];
  const float* fp_w = (const float*)d_in[18];
  const float* fp_b = (const float*)d_in[19];
  float* out = (float*)d_out;

  char* ws = (char*)d_ws;
  bf16_t* xf_ln = (bf16_t*)ws;                   // [65536,1024] bf16; later xf [65536,512]
  bf16_t* hbuf  = (bf16_t*)(ws + 134217728ULL);  // [65536,1024] bf16
  char* sm = ws + 268435456ULL;
  bf16_t* w1t  = (bf16_t*)sm;                    // [1024,1024] 2 MiB
  bf16_t* w2t  = (bf16_t*)(sm + 2097152ULL);     // [512,1024] 1 MiB
  bf16_t* fpt  = (bf16_t*)(sm + 3145728ULL);     // [2048,512] 2 MiB
  float*  a_s  = (float*)(sm + 5242880ULL);      // [65536,8] 2 MiB
  float*  xg   = (float*)(sm + 7340032ULL);      // [64,512] 128 KiB
  float*  wd_att = (float*)(sm + 7471104ULL);    // [512,8] 16 KiB
  float*  wsatt  = (float*)(sm + 7487488ULL);    // [512,8] 16 KiB
  float*  zbuf4  = (float*)(sm + 7503872ULL);    // [64,4,8,512] 4 MiB
  float*  aggx   = (float*)(sm + 11698176ULL);   // [64,512] 128 KiB
  bf16_t* xf = xf_ln;  // [65536,512] after G2 (xf_ln dead)

  // merged weight prep + global LN
  k_prep<<<2628, 256, 0, stream>>>(ip_w1, ip_w2, fp_w, gat_wd, att_d, gat_ws,
                                   att_s, x_global, ng_g, ng_b, w1t, w2t, fpt,
                                   wd_att, wsatt, xg);

  // fine LN
  k_ln_fine<<<65536, 256, 0, stream>>>(x_fine, nf_g, nf_b, xf_ln);

  // MLP (m97-structure MFMA GEMMs, XCD-affine A-panel grouping)
  gemm_bt<1024, 1024, 0><<<4096, 256, 0, stream>>>(xf_ln, w1t, ip_b1, hbuf);
  gemm_bt<512, 1024, 1><<<2048, 256, 0, stream>>>(hbuf, w2t, ip_b2, xf);

  // attention chain (GEMM3 eliminated by linearity of gat_ws)
  k_as<<<512, 256, 0, stream>>>(xf, wsatt, a_s);
  k_alpha_z<<<256, 512, 0, stream>>>(a_s, xf, xg, wd_att, zbuf4);
  k_fin<<<64, 512, 0, stream>>>(zbuf4, gat_ws, gat_bias, xg, aggx);
  k_og<<<dim3(8, 64), 256, 0, stream>>>(aggx, gp_w, gp_b, out);

  // fine projection straight into strided output rows
  gemm_bt<2048, 512, 3><<<8192, 256, 0, stream>>>(xf, fpt, fp_b, out);
}